// Round 2
// baseline (265.840 us; speedup 1.0000x reference)
//
#include <hip/hip_runtime.h>
#include <hip/hip_bf16.h>
#include <stdint.h>

// Problem constants (from reference): B=2, L=4096, H=1024
#define BB 2
#define LL 4096
#define HH 1024

typedef __bf16 bf16;
typedef __bf16 bf16x4 __attribute__((ext_vector_type(4)));
typedef __bf16 bf16x8 __attribute__((ext_vector_type(8)));
typedef float  f32x4  __attribute__((ext_vector_type(4)));

// ---------------------------------------------------------------------------
// RoPE: h[b,l,i] = x*cos + rotate_half(x)*sin, fp32 in -> bf16 out [B,L,H]
// rotate_half: i<H/2 -> -x[i+H/2];  i>=H/2 -> x[i-H/2]
// grid (L, B), block 128; each thread handles 4 lower + 4 upper elements.
// ---------------------------------------------------------------------------
__global__ __launch_bounds__(128) void rope_kernel(
    const float* __restrict__ x, const float* __restrict__ cs,
    const float* __restrict__ sn, bf16* __restrict__ h)
{
    const int l = blockIdx.x;
    const int b = blockIdx.y;
    const int i = threadIdx.x * 4;            // 0..508
    const long xb = ((long)b * LL + l) * HH;
    const long cb = (long)l * HH;

    const float4 x1 = *(const float4*)(x + xb + i);
    const float4 x2 = *(const float4*)(x + xb + i + HH / 2);
    const float4 c1 = *(const float4*)(cs + cb + i);
    const float4 c2 = *(const float4*)(cs + cb + i + HH / 2);
    const float4 s1 = *(const float4*)(sn + cb + i);
    const float4 s2 = *(const float4*)(sn + cb + i + HH / 2);

    bf16x4 o1, o2;
    o1[0] = (bf16)(x1.x * c1.x - x2.x * s1.x);
    o1[1] = (bf16)(x1.y * c1.y - x2.y * s1.y);
    o1[2] = (bf16)(x1.z * c1.z - x2.z * s1.z);
    o1[3] = (bf16)(x1.w * c1.w - x2.w * s1.w);
    o2[0] = (bf16)(x2.x * c2.x + x1.x * s2.x);
    o2[1] = (bf16)(x2.y * c2.y + x1.y * s2.y);
    o2[2] = (bf16)(x2.z * c2.z + x1.z * s2.z);
    o2[3] = (bf16)(x2.w * c2.w + x1.w * s2.w);

    *(bf16x4*)(h + xb + i)          = o1;
    *(bf16x4*)(h + xb + i + HH / 2) = o2;
}

// ---------------------------------------------------------------------------
// bf16 transpose [R,C] -> [C,R], batched over z. 64x64 tiles, 256 threads.
// Packs row-pairs into u32 words so all LDS traffic is b32 (2-way max = free).
// R1 FIX: store phase now writes 2x uint4 per thread (32 B) — previous
// version only covered half the tile (u32 cols 0..15 of 0..31), leaving
// hT[*, r0+32..63] poisoned -> half the Gram-matrix terms dropped.
// ---------------------------------------------------------------------------
__global__ __launch_bounds__(256) void transpose_bf16_64(
    const bf16* __restrict__ in, bf16* __restrict__ out, const int R, const int C)
{
    __shared__ uint32_t lds[64][36];          // [col][row-pair], pad 32->36 keeps 16B alignment
    const long zoff = (long)blockIdx.z * R * C;
    const int r0 = blockIdx.x * 64;
    const int c0 = blockIdx.y * 64;
    const int t  = threadIdx.x;

    // load: thread covers rows (2rr, 2rr+1), cols c8*8..+7  (16B per row)
    const int c8 = t & 7;
    const int rr = t >> 3;                    // 0..31
    const bf16* p0 = in + zoff + (long)(r0 + 2 * rr) * C + c0 + c8 * 8;
    const uint4 ra = *(const uint4*)p0;
    const uint4 rb = *(const uint4*)(p0 + C);
    const uint32_t av[4] = {ra.x, ra.y, ra.z, ra.w};
    const uint32_t bv[4] = {rb.x, rb.y, rb.z, rb.w};
#pragma unroll
    for (int j = 0; j < 4; ++j) {
        const uint32_t alo = av[j] & 0xffffu, ahi = av[j] >> 16;
        const uint32_t blo = bv[j] & 0xffffu, bhi = bv[j] >> 16;
        lds[c8 * 8 + 2 * j    ][rr] = alo | (blo << 16);  // out[col][2rr], out[col][2rr+1]
        lds[c8 * 8 + 2 * j + 1][rr] = ahi | (bhi << 16);
    }
    __syncthreads();

    // store: 4 threads per output row c; each writes 32 B (u32 cols q*8..q*8+7)
    const int c = t >> 2;                     // 0..63
    const int q = t & 3;                      // 0..3
    const uint4 w0 = *(const uint4*)&lds[c][q * 8];
    const uint4 w1 = *(const uint4*)&lds[c][q * 8 + 4];
    bf16* po = out + zoff + (long)(c0 + c) * R + r0 + q * 16;
    *(uint4*)(po)     = w0;
    *(uint4*)(po + 8) = w1;
}

// ---------------------------------------------------------------------------
// W_q fp32 [H,H] -> Wt bf16 [H,H], Wt[i][o] = W_q[o][i]. 32x32 tiles.
// ---------------------------------------------------------------------------
__global__ __launch_bounds__(1024) void transpose_wq(
    const float* __restrict__ Wq, bf16* __restrict__ Wt)
{
    __shared__ float lds[32][33];
    const int r0 = blockIdx.x * 32;           // o tile
    const int c0 = blockIdx.y * 32;           // i tile
    const int tx = threadIdx.x, ty = threadIdx.y;
    lds[ty][tx] = Wq[(long)(r0 + ty) * HH + c0 + tx];
    __syncthreads();
    Wt[(long)(c0 + ty) * HH + r0 + tx] = (bf16)lds[tx][ty];
}

// ---------------------------------------------------------------------------
// C[m,n] = sum_k A[m,k] * B[n,k]   (A: [M,K] bf16, B: [N,K] bf16, row-major)
// 128x128 tile, BK=32, 4 waves (2x2 of 64x64), 16x16x32 bf16 MFMA.
// Batched via blockIdx.z with element strides sA/sB/sC (sB=0 to broadcast B).
// ---------------------------------------------------------------------------
template <typename OUT_T>
__global__ __launch_bounds__(256) void gemm_bt(
    const bf16* __restrict__ A, const bf16* __restrict__ B, OUT_T* __restrict__ C,
    const int M, const int N, const int K,
    const long sA, const long sB, const long sC)
{
    constexpr int BM = 128, BN = 128, BK = 32;
    __shared__ __align__(16) bf16 As[BM][BK];   // 8 KB
    __shared__ __align__(16) bf16 Bs[BN][BK];   // 8 KB

    const bf16* Ab = A + blockIdx.z * sA;
    const bf16* Bb = B + blockIdx.z * sB;
    OUT_T*      Cb = C + blockIdx.z * sC;

    const int m0 = blockIdx.x * BM;
    const int n0 = blockIdx.y * BN;
    const int tid  = threadIdx.x;
    const int lane = tid & 63;
    const int wave = tid >> 6;
    const int wm = (wave & 1) * 64;
    const int wn = (wave >> 1) * 64;
    const int fr = lane & 15;                 // fragment row (m or n)
    const int fq = lane >> 4;                 // k-quad

    // staging: thread loads 16B (8 bf16); 4 threads per row, rows 0..63 (+64)
    const int srow = tid >> 2;
    const int scol = (tid & 3) * 8;
    const bf16* Ag = Ab + (long)(m0 + srow) * K + scol;
    const bf16* Bg = Bb + (long)(n0 + srow) * K + scol;

    const f32x4 vzero = {0.f, 0.f, 0.f, 0.f};
    f32x4 acc[4][4];
#pragma unroll
    for (int i = 0; i < 4; ++i)
#pragma unroll
        for (int j = 0; j < 4; ++j) acc[i][j] = vzero;

    for (int k0 = 0; k0 < K; k0 += BK) {
        const uint4 a0 = *(const uint4*)(Ag + k0);
        const uint4 a1 = *(const uint4*)(Ag + k0 + 64L * K);
        const uint4 b0 = *(const uint4*)(Bg + k0);
        const uint4 b1 = *(const uint4*)(Bg + k0 + 64L * K);
        __syncthreads();                      // everyone done reading previous tile
        *(uint4*)&As[srow     ][scol] = a0;
        *(uint4*)&As[srow + 64][scol] = a1;
        *(uint4*)&Bs[srow     ][scol] = b0;
        *(uint4*)&Bs[srow + 64][scol] = b1;
        __syncthreads();

        bf16x8 af[4], bfv[4];
#pragma unroll
        for (int i = 0; i < 4; ++i) af[i]  = *(const bf16x8*)&As[wm + i * 16 + fr][fq * 8];
#pragma unroll
        for (int j = 0; j < 4; ++j) bfv[j] = *(const bf16x8*)&Bs[wn + j * 16 + fr][fq * 8];
#pragma unroll
        for (int i = 0; i < 4; ++i)
#pragma unroll
            for (int j = 0; j < 4; ++j)
                acc[i][j] = __builtin_amdgcn_mfma_f32_16x16x32_bf16(af[i], bfv[j], acc[i][j], 0, 0, 0);
    }

    // epilogue: C/D layout col = lane&15, row = (lane>>4)*4 + reg  [m89/m91-verified]
#pragma unroll
    for (int i = 0; i < 4; ++i) {
#pragma unroll
        for (int r = 0; r < 4; ++r) {
            const int row = m0 + wm + i * 16 + fq * 4 + r;
#pragma unroll
            for (int j = 0; j < 4; ++j) {
                const int col = n0 + wn + j * 16 + fr;
                Cb[(long)row * N + col] = (OUT_T)acc[i][j][r];
            }
        }
    }
}

// ---------------------------------------------------------------------------
// O = h @ (W_q^T @ (h^T h)) per batch  — associativity-reordered reference.
// Workspace layout (42 MB total):
//   h  bf16 [B,L,H]  @ 0        (16 MB)
//   hT bf16 [B,H,L]  @ 16 MB    (16 MB)
//   Wt bf16 [H,H]    @ 32 MB    ( 2 MB)   Wt[i][o] = W_q[o][i]
//   G  bf16 [B,H,H]  @ 34 MB    ( 4 MB)   G = h^T h   (symmetric)
//   Mt bf16 [B,H,H]  @ 38 MB    ( 4 MB)   Mt = G @ W_q = (W_q^T G)^T
// ---------------------------------------------------------------------------
extern "C" void kernel_launch(void* const* d_in, const int* in_sizes, int n_in,
                              void* d_out, int out_size, void* d_ws, size_t ws_size,
                              hipStream_t stream)
{
    const float* x  = (const float*)d_in[0];   // hidden_states [B,L,H]
    const float* Wq = (const float*)d_in[1];   // [H,H]
    const float* cs = (const float*)d_in[2];   // [L,H]
    const float* sn = (const float*)d_in[3];   // [L,H]
    float* out = (float*)d_out;                // [B,L,H] fp32
    char* ws = (char*)d_ws;

    bf16* h  = (bf16*)(ws);
    bf16* hT = (bf16*)(ws + 16u * 1024 * 1024);
    bf16* Wt = (bf16*)(ws + 32u * 1024 * 1024);
    bf16* G  = (bf16*)(ws + 34u * 1024 * 1024);
    bf16* Mt = (bf16*)(ws + 38u * 1024 * 1024);

    // 1) RoPE -> bf16 h
    rope_kernel<<<dim3(LL, BB), 128, 0, stream>>>(x, cs, sn, h);

    // 2) h -> hT (per batch [L,H] -> [H,L]) so the G GEMM has K contiguous
    transpose_bf16_64<<<dim3(LL / 64, HH / 64, BB), 256, 0, stream>>>(h, hT, LL, HH);

    // 3) W_q -> Wt = W_q^T in bf16
    transpose_wq<<<dim3(HH / 32, HH / 32), dim3(32, 32), 0, stream>>>(Wq, Wt);

    // 4) G_b = hT_b @ hT_b^T : [H,H], K=L
    gemm_bt<bf16><<<dim3(HH / 128, HH / 128, BB), 256, 0, stream>>>(
        hT, hT, G, HH, HH, LL, (long)HH * LL, (long)HH * LL, (long)HH * HH);

    // 5) Mt_b = G_b @ Wt^T : Mt[j,i] = sum_o G[j,o] W_q[o,i] = (W_q^T G)^T  (B broadcast)
    gemm_bt<bf16><<<dim3(HH / 128, HH / 128, BB), 256, 0, stream>>>(
        G, Wt, Mt, HH, HH, HH, (long)HH * HH, 0L, (long)HH * HH);

    // 6) O_b = h_b @ Mt_b^T : O[l,j] = sum_i h[l,i] Mt[j,i]  -> fp32 out
    gemm_bt<float><<<dim3(LL / 128, HH / 128, BB), 256, 0, stream>>>(
        h, Mt, out, LL, HH, HH, (long)LL * HH, (long)HH * HH, (long)LL * HH);
}

// Round 3
// 218.938 us; speedup vs baseline: 1.2142x; 1.2142x over previous
//
#include <hip/hip_runtime.h>
#include <hip/hip_bf16.h>
#include <stdint.h>

// Problem constants (from reference): B=2, L=4096, H=1024
#define BB 2
#define LL 4096
#define HH 1024

typedef __bf16 bf16;
typedef __bf16 bf16x4 __attribute__((ext_vector_type(4)));
typedef __bf16 bf16x8 __attribute__((ext_vector_type(8)));
typedef float  f32x4  __attribute__((ext_vector_type(4)));

// ---------------------------------------------------------------------------
// async global->LDS, 16 B per lane. LDS dest = wave-uniform base + lane*16
// (m104/m108 semantics). CK-style casts via uintptr_t.
// ---------------------------------------------------------------------------
__device__ __forceinline__ void async_cp16(const bf16* g, const bf16* l)
{
    typedef const uint32_t __attribute__((address_space(1)))* gp_t;
    typedef uint32_t __attribute__((address_space(3)))* lp_t;
    __builtin_amdgcn_global_load_lds((gp_t)(uintptr_t)g, (lp_t)(uintptr_t)l, 16, 0, 0);
}

// ---------------------------------------------------------------------------
// RoPE: h[b,l,i] = x*cos + rotate_half(x)*sin, fp32 in -> bf16 out [B,L,H]
// ---------------------------------------------------------------------------
__global__ __launch_bounds__(128) void rope_kernel(
    const float* __restrict__ x, const float* __restrict__ cs,
    const float* __restrict__ sn, bf16* __restrict__ h)
{
    const int l = blockIdx.x;
    const int b = blockIdx.y;
    const int i = threadIdx.x * 4;            // 0..508
    const long xb = ((long)b * LL + l) * HH;
    const long cb = (long)l * HH;

    const float4 x1 = *(const float4*)(x + xb + i);
    const float4 x2 = *(const float4*)(x + xb + i + HH / 2);
    const float4 c1 = *(const float4*)(cs + cb + i);
    const float4 c2 = *(const float4*)(cs + cb + i + HH / 2);
    const float4 s1 = *(const float4*)(sn + cb + i);
    const float4 s2 = *(const float4*)(sn + cb + i + HH / 2);

    bf16x4 o1, o2;
    o1[0] = (bf16)(x1.x * c1.x - x2.x * s1.x);
    o1[1] = (bf16)(x1.y * c1.y - x2.y * s1.y);
    o1[2] = (bf16)(x1.z * c1.z - x2.z * s1.z);
    o1[3] = (bf16)(x1.w * c1.w - x2.w * s1.w);
    o2[0] = (bf16)(x2.x * c2.x + x1.x * s2.x);
    o2[1] = (bf16)(x2.y * c2.y + x1.y * s2.y);
    o2[2] = (bf16)(x2.z * c2.z + x1.z * s2.z);
    o2[3] = (bf16)(x2.w * c2.w + x1.w * s2.w);

    *(bf16x4*)(h + xb + i)          = o1;
    *(bf16x4*)(h + xb + i + HH / 2) = o2;
}

// ---------------------------------------------------------------------------
// bf16 transpose [R,C] -> [C,R], batched over z. 64x64 tiles, 256 threads.
// ---------------------------------------------------------------------------
__global__ __launch_bounds__(256) void transpose_bf16_64(
    const bf16* __restrict__ in, bf16* __restrict__ out, const int R, const int C)
{
    __shared__ uint32_t lds[64][36];
    const long zoff = (long)blockIdx.z * R * C;
    const int r0 = blockIdx.x * 64;
    const int c0 = blockIdx.y * 64;
    const int t  = threadIdx.x;

    const int c8 = t & 7;
    const int rr = t >> 3;                    // 0..31
    const bf16* p0 = in + zoff + (long)(r0 + 2 * rr) * C + c0 + c8 * 8;
    const uint4 ra = *(const uint4*)p0;
    const uint4 rb = *(const uint4*)(p0 + C);
    const uint32_t av[4] = {ra.x, ra.y, ra.z, ra.w};
    const uint32_t bv[4] = {rb.x, rb.y, rb.z, rb.w};
#pragma unroll
    for (int j = 0; j < 4; ++j) {
        const uint32_t alo = av[j] & 0xffffu, ahi = av[j] >> 16;
        const uint32_t blo = bv[j] & 0xffffu, bhi = bv[j] >> 16;
        lds[c8 * 8 + 2 * j    ][rr] = alo | (blo << 16);
        lds[c8 * 8 + 2 * j + 1][rr] = ahi | (bhi << 16);
    }
    __syncthreads();

    const int c = t >> 2;                     // 0..63
    const int q = t & 3;                      // 0..3
    const uint4 w0 = *(const uint4*)&lds[c][q * 8];
    const uint4 w1 = *(const uint4*)&lds[c][q * 8 + 4];
    bf16* po = out + zoff + (long)(c0 + c) * R + r0 + q * 16;
    *(uint4*)(po)     = w0;
    *(uint4*)(po + 8) = w1;
}

// ---------------------------------------------------------------------------
// W_q fp32 [H,H] -> Wt bf16 [H,H], Wt[i][o] = W_q[o][i]. 32x32 tiles.
// ---------------------------------------------------------------------------
__global__ __launch_bounds__(1024) void transpose_wq(
    const float* __restrict__ Wq, bf16* __restrict__ Wt)
{
    __shared__ float lds[32][33];
    const int r0 = blockIdx.x * 32;
    const int c0 = blockIdx.y * 32;
    const int tx = threadIdx.x, ty = threadIdx.y;
    lds[ty][tx] = Wq[(long)(r0 + ty) * HH + c0 + tx];
    __syncthreads();
    Wt[(long)(c0 + ty) * HH + r0 + tx] = (bf16)lds[tx][ty];
}

// ---------------------------------------------------------------------------
// Shared GEMM macros: C[m,n] = sum_k A[m,k]*B[n,k]; 128x128 tile, BK=32,
// 4 waves (2x2 of 64x64), 16x16x32 bf16 MFMA, global_load_lds staging.
// Thread tid stages 16 B at LDS byte offset tid*16 per 4 KB pass; the
// matching global element is row tid>>2, cols (tid&3)*8..+7 — contiguous
// in lane order, as global_load_lds requires.
// ---------------------------------------------------------------------------
#define GEMM_PROLOGUE()                                                        \
    constexpr int BM = 128, BN = 128, BK = 32;                                 \
    (void)BM; (void)BN;                                                        \
    __shared__ __align__(16) bf16 As[128][32];                                 \
    __shared__ __align__(16) bf16 Bs[128][32];                                 \
    const int m0 = blockIdx.x * 128;                                           \
    const int n0 = blockIdx.y * 128;                                           \
    const int tid  = threadIdx.x;                                              \
    const int lane = tid & 63;                                                 \
    const int wave = tid >> 6;                                                 \
    const int wm = (wave & 1) * 64;                                            \
    const int wn = (wave >> 1) * 64;                                           \
    const int fr = lane & 15;                                                  \
    const int fq = lane >> 4;                                                  \
    const int srow = tid >> 2;                                                 \
    const int scol = (tid & 3) * 8;                                            \
    bf16* asw0 = &As[0][0] + wave * 512;        /* pass0: rows 0..63  */       \
    bf16* asw1 = &As[0][0] + 2048 + wave * 512; /* pass1: rows 64..127*/       \
    bf16* bsw0 = &Bs[0][0] + wave * 512;                                       \
    bf16* bsw1 = &Bs[0][0] + 2048 + wave * 512;                                \
    const bf16* Ag = Ab + (long)(m0 + srow) * K + scol;                        \
    const bf16* Bg = Bb + (long)(n0 + srow) * K + scol;                        \
    const f32x4 vzero = {0.f, 0.f, 0.f, 0.f};                                  \
    f32x4 acc[4][4];                                                           \
    _Pragma("unroll") for (int i = 0; i < 4; ++i)                              \
        _Pragma("unroll") for (int j = 0; j < 4; ++j) acc[i][j] = vzero;

#define GEMM_KLOOP(KBASE, KEND)                                                \
    for (int k0 = (KBASE); k0 < (KEND); k0 += BK) {                            \
        __syncthreads();                     /* prev-tile reads complete */    \
        async_cp16(Ag + k0,            asw0);                                  \
        async_cp16(Ag + k0 + 64L * K,  asw1);                                  \
        async_cp16(Bg + k0,            bsw0);                                  \
        async_cp16(Bg + k0 + 64L * K,  bsw1);                                  \
        __syncthreads();                     /* drains vmcnt before barrier */ \
        bf16x8 af[4], bfv[4];                                                  \
        _Pragma("unroll") for (int i = 0; i < 4; ++i)                          \
            af[i]  = *(const bf16x8*)&As[wm + i * 16 + fr][fq * 8];            \
        _Pragma("unroll") for (int j = 0; j < 4; ++j)                          \
            bfv[j] = *(const bf16x8*)&Bs[wn + j * 16 + fr][fq * 8];            \
        _Pragma("unroll") for (int i = 0; i < 4; ++i)                          \
            _Pragma("unroll") for (int j = 0; j < 4; ++j)                      \
                acc[i][j] = __builtin_amdgcn_mfma_f32_16x16x32_bf16(           \
                    af[i], bfv[j], acc[i][j], 0, 0, 0);                        \
    }

// epilogue C/D layout: col = lane&15, row = (lane>>4)*4 + reg [m89/m91]
#define GEMM_EPILOGUE(DST, DT)                                                 \
    _Pragma("unroll") for (int i = 0; i < 4; ++i) {                            \
        _Pragma("unroll") for (int r = 0; r < 4; ++r) {                        \
            const int row = m0 + wm + i * 16 + fq * 4 + r;                     \
            _Pragma("unroll") for (int j = 0; j < 4; ++j) {                    \
                const int col = n0 + wn + j * 16 + fr;                         \
                (DST)[(long)row * N + col] = (DT)acc[i][j][r];                 \
            }                                                                  \
        }                                                                      \
    }

// full-K GEMM, batched via blockIdx.z (sB=0 broadcasts B)
template <typename OUT_T>
__global__ __launch_bounds__(256) void gemm_bt(
    const bf16* __restrict__ A, const bf16* __restrict__ B, OUT_T* __restrict__ C,
    const int M, const int N, const int K,
    const long sA, const long sB, const long sC)
{
    const bf16* Ab = A + blockIdx.z * sA;
    const bf16* Bb = B + blockIdx.z * sB;
    OUT_T*      Cb = C + blockIdx.z * sC;
    GEMM_PROLOGUE();
    GEMM_KLOOP(0, K);
    GEMM_EPILOGUE(Cb, OUT_T);
}

// split-K GEMM: blockIdx.z = batch*S + split; fp32 partials P[z][M*N]
__global__ __launch_bounds__(256) void gemm_splitk(
    const bf16* __restrict__ A, const bf16* __restrict__ B, float* __restrict__ P,
    const int M, const int N, const int K, const int Ksplit, const int S,
    const long sA, const long sB)
{
    const int zb = blockIdx.z / S;
    const int zs = blockIdx.z % S;
    const bf16* Ab = A + zb * sA;
    const bf16* Bb = B + zb * sB;
    float* Pb = P + (long)blockIdx.z * M * N;
    const int kbase = zs * Ksplit;
    GEMM_PROLOGUE();
    GEMM_KLOOP(kbase, kbase + Ksplit);
    GEMM_EPILOGUE(Pb, float);
}

// sum S fp32 partial planes -> bf16. grid (npb/1024, B), block 256.
__global__ __launch_bounds__(256) void reduce_splits(
    const float* __restrict__ P, bf16* __restrict__ out, const int npb, const int S)
{
    const int b = blockIdx.y;
    const long r = ((long)blockIdx.x * 256 + threadIdx.x) * 4;
    const float* base = P + (long)b * S * npb + r;
    float4 a = *(const float4*)(base);
    for (int s = 1; s < S; ++s) {
        const float4 v = *(const float4*)(base + (long)s * npb);
        a.x += v.x; a.y += v.y; a.z += v.z; a.w += v.w;
    }
    bf16x4 o;
    o[0] = (bf16)a.x; o[1] = (bf16)a.y; o[2] = (bf16)a.z; o[3] = (bf16)a.w;
    *(bf16x4*)(out + (long)b * npb + r) = o;
}

// ---------------------------------------------------------------------------
// O = h @ (W_q^T @ (h^T h)) per batch  — associativity-reordered reference.
// Workspace (106 MB when split-K enabled):
//   h  bf16 [B,L,H]  @ 0      | hT bf16 [B,H,L] @ 16M | Wt bf16 [H,H] @ 32M
//   G  bf16 [B,H,H]  @ 34M    | Mt bf16 [B,H,H] @ 38M | P fp32 (64 MB) @ 42M
// ---------------------------------------------------------------------------
extern "C" void kernel_launch(void* const* d_in, const int* in_sizes, int n_in,
                              void* d_out, int out_size, void* d_ws, size_t ws_size,
                              hipStream_t stream)
{
    const float* x  = (const float*)d_in[0];   // hidden_states [B,L,H]
    const float* Wq = (const float*)d_in[1];   // [H,H]
    const float* cs = (const float*)d_in[2];   // [L,H]
    const float* sn = (const float*)d_in[3];   // [L,H]
    float* out = (float*)d_out;                // [B,L,H] fp32
    char* ws = (char*)d_ws;

    bf16*  h  = (bf16*)(ws);
    bf16*  hT = (bf16*)(ws + 16u * 1024 * 1024);
    bf16*  Wt = (bf16*)(ws + 32u * 1024 * 1024);
    bf16*  G  = (bf16*)(ws + 34u * 1024 * 1024);
    bf16*  Mt = (bf16*)(ws + 38u * 1024 * 1024);
    float* P  = (float*)(ws + 42u * 1024 * 1024);   // 16 planes of H*H fp32

    const bool big_ws = ws_size >= (size_t)106 * 1024 * 1024;

    // 1) RoPE -> bf16 h
    rope_kernel<<<dim3(LL, BB), 128, 0, stream>>>(x, cs, sn, h);

    // 2) h -> hT (per batch [L,H] -> [H,L]) so the G GEMM has K contiguous
    transpose_bf16_64<<<dim3(LL / 64, HH / 64, BB), 256, 0, stream>>>(h, hT, LL, HH);

    // 3) W_q -> Wt = W_q^T in bf16
    transpose_wq<<<dim3(HH / 32, HH / 32), dim3(32, 32), 0, stream>>>(Wq, Wt);

    if (big_ws) {
        // 4) G_b = hT_b @ hT_b^T, K=4096 split 8 ways -> 1024 blocks (4/CU)
        gemm_splitk<<<dim3(HH / 128, HH / 128, BB * 8), 256, 0, stream>>>(
            hT, hT, P, HH, HH, LL, LL / 8, 8, (long)HH * LL, (long)HH * LL);
        reduce_splits<<<dim3(HH * HH / 1024, BB), 256, 0, stream>>>(P, G, HH * HH, 8);

        // 5) Mt_b = G_b @ Wt^T, K=1024 split 4 ways -> 512 blocks
        gemm_splitk<<<dim3(HH / 128, HH / 128, BB * 4), 256, 0, stream>>>(
            G, Wt, P, HH, HH, HH, HH / 4, 4, (long)HH * HH, 0L);
        reduce_splits<<<dim3(HH * HH / 1024, BB), 256, 0, stream>>>(P, Mt, HH * HH, 4);
    } else {
        // fallback: unsplit (latency-bound but correct in 42 MB ws)
        gemm_bt<bf16><<<dim3(HH / 128, HH / 128, BB), 256, 0, stream>>>(
            hT, hT, G, HH, HH, LL, (long)HH * LL, (long)HH * LL, (long)HH * HH);
        gemm_bt<bf16><<<dim3(HH / 128, HH / 128, BB), 256, 0, stream>>>(
            G, Wt, Mt, HH, HH, HH, (long)HH * HH, 0L, (long)HH * HH);
    }

    // 6) O_b = h_b @ Mt_b^T : O[l,j] = sum_i h[l,i] Mt[j,i]  -> fp32 out
    gemm_bt<float><<<dim3(LL / 128, HH / 128, BB), 256, 0, stream>>>(
        h, Mt, out, LL, HH, HH, (long)LL * HH, (long)HH * HH, (long)LL * HH);
}

// Round 4
// 210.244 us; speedup vs baseline: 1.2644x; 1.0413x over previous
//
#include <hip/hip_runtime.h>
#include <hip/hip_bf16.h>
#include <stdint.h>

// Problem constants (from reference): B=2, L=4096, H=1024
#define BB 2
#define LL 4096
#define HH 1024

typedef __bf16 bf16;
typedef __bf16 bf16x4 __attribute__((ext_vector_type(4)));
typedef __bf16 bf16x8 __attribute__((ext_vector_type(8)));
typedef float  f32x4  __attribute__((ext_vector_type(4)));

// ---------------------------------------------------------------------------
// async global->LDS, 16 B per lane. LDS dest = wave-uniform base + lane*16
// (m104/m108 semantics).
// ---------------------------------------------------------------------------
__device__ __forceinline__ void async_cp16(const bf16* g, const bf16* l)
{
    typedef const uint32_t __attribute__((address_space(1)))* gp_t;
    typedef uint32_t __attribute__((address_space(3)))* lp_t;
    __builtin_amdgcn_global_load_lds((gp_t)(uintptr_t)g, (lp_t)(uintptr_t)l, 16, 0, 0);
}

// ---------------------------------------------------------------------------
// RoPE: h[b,l,i] = x*cos + rotate_half(x)*sin, fp32 in -> bf16 out [B,L,H]
// ---------------------------------------------------------------------------
__global__ __launch_bounds__(128) void rope_kernel(
    const float* __restrict__ x, const float* __restrict__ cs,
    const float* __restrict__ sn, bf16* __restrict__ h)
{
    const int l = blockIdx.x;
    const int b = blockIdx.y;
    const int i = threadIdx.x * 4;            // 0..508
    const long xb = ((long)b * LL + l) * HH;
    const long cb = (long)l * HH;

    const float4 x1 = *(const float4*)(x + xb + i);
    const float4 x2 = *(const float4*)(x + xb + i + HH / 2);
    const float4 c1 = *(const float4*)(cs + cb + i);
    const float4 c2 = *(const float4*)(cs + cb + i + HH / 2);
    const float4 s1 = *(const float4*)(sn + cb + i);
    const float4 s2 = *(const float4*)(sn + cb + i + HH / 2);

    bf16x4 o1, o2;
    o1[0] = (bf16)(x1.x * c1.x - x2.x * s1.x);
    o1[1] = (bf16)(x1.y * c1.y - x2.y * s1.y);
    o1[2] = (bf16)(x1.z * c1.z - x2.z * s1.z);
    o1[3] = (bf16)(x1.w * c1.w - x2.w * s1.w);
    o2[0] = (bf16)(x2.x * c2.x + x1.x * s2.x);
    o2[1] = (bf16)(x2.y * c2.y + x1.y * s2.y);
    o2[2] = (bf16)(x2.z * c2.z + x1.z * s2.z);
    o2[3] = (bf16)(x2.w * c2.w + x1.w * s2.w);

    *(bf16x4*)(h + xb + i)          = o1;
    *(bf16x4*)(h + xb + i + HH / 2) = o2;
}

// ---------------------------------------------------------------------------
// bf16 transpose [R,C] -> [C,R], batched over z. 64x64 tiles, 256 threads.
// ---------------------------------------------------------------------------
__global__ __launch_bounds__(256) void transpose_bf16_64(
    const bf16* __restrict__ in, bf16* __restrict__ out, const int R, const int C)
{
    __shared__ uint32_t lds[64][36];
    const long zoff = (long)blockIdx.z * R * C;
    const int r0 = blockIdx.x * 64;
    const int c0 = blockIdx.y * 64;
    const int t  = threadIdx.x;

    const int c8 = t & 7;
    const int rr = t >> 3;                    // 0..31
    const bf16* p0 = in + zoff + (long)(r0 + 2 * rr) * C + c0 + c8 * 8;
    const uint4 ra = *(const uint4*)p0;
    const uint4 rb = *(const uint4*)(p0 + C);
    const uint32_t av[4] = {ra.x, ra.y, ra.z, ra.w};
    const uint32_t bv[4] = {rb.x, rb.y, rb.z, rb.w};
#pragma unroll
    for (int j = 0; j < 4; ++j) {
        const uint32_t alo = av[j] & 0xffffu, ahi = av[j] >> 16;
        const uint32_t blo = bv[j] & 0xffffu, bhi = bv[j] >> 16;
        lds[c8 * 8 + 2 * j    ][rr] = alo | (blo << 16);
        lds[c8 * 8 + 2 * j + 1][rr] = ahi | (bhi << 16);
    }
    __syncthreads();

    const int c = t >> 2;                     // 0..63
    const int q = t & 3;                      // 0..3
    const uint4 w0 = *(const uint4*)&lds[c][q * 8];
    const uint4 w1 = *(const uint4*)&lds[c][q * 8 + 4];
    bf16* po = out + zoff + (long)(c0 + c) * R + r0 + q * 16;
    *(uint4*)(po)     = w0;
    *(uint4*)(po + 8) = w1;
}

// ---------------------------------------------------------------------------
// W_q fp32 [H,H] -> Wt bf16 [H,H], Wt[i][o] = W_q[o][i]. 32x32 tiles.
// ---------------------------------------------------------------------------
__global__ __launch_bounds__(1024) void transpose_wq(
    const float* __restrict__ Wq, bf16* __restrict__ Wt)
{
    __shared__ float lds[32][33];
    const int r0 = blockIdx.x * 32;
    const int c0 = blockIdx.y * 32;
    const int tx = threadIdx.x, ty = threadIdx.y;
    lds[ty][tx] = Wq[(long)(r0 + ty) * HH + c0 + tx];
    __syncthreads();
    Wt[(long)(c0 + ty) * HH + r0 + tx] = (bf16)lds[tx][ty];
}

// ---------------------------------------------------------------------------
// Shared GEMM macros: C[m,n] = sum_k A[m,k]*B[n,k]; 128x128 tile, BK=32,
// 4 waves (2x2 of 64x64), 16x16x32 bf16 MFMA.
// R3: double-buffered LDS (2x16 KB) with depth-1 async prefetch: tile k+1's
// global_load_lds is issued right after the barrier, so it is in flight
// across the entire compute phase of tile k instead of being drained
// immediately by vmcnt(0) with no work in between (latency-bound fix).
// Hazards: barrier k implies lgkmcnt(0) (prev ds_reads done) before any wave
// writes buf^1; tile-k loads (issued iter k-1) are drained by barrier k.
// ---------------------------------------------------------------------------
#define GEMM_PROLOGUE()                                                        \
    constexpr int BK = 32;                                                     \
    __shared__ __align__(16) bf16 As[2][128][32];                              \
    __shared__ __align__(16) bf16 Bs[2][128][32];                              \
    const int m0 = blockIdx.x * 128;                                           \
    const int n0 = blockIdx.y * 128;                                           \
    const int tid  = threadIdx.x;                                              \
    const int lane = tid & 63;                                                 \
    const int wave = tid >> 6;                                                 \
    const int wm = (wave & 1) * 64;                                            \
    const int wn = (wave >> 1) * 64;                                           \
    const int fr = lane & 15;                                                  \
    const int fq = lane >> 4;                                                  \
    const int srow = tid >> 2;                                                 \
    const int scol = (tid & 3) * 8;                                            \
    const int woff0 = wave * 512;          /* pass0: rows 0..63  */            \
    const int woff1 = 2048 + wave * 512;   /* pass1: rows 64..127*/            \
    const bf16* Ag = Ab + (long)(m0 + srow) * K + scol;                        \
    const bf16* Bg = Bb + (long)(n0 + srow) * K + scol;                        \
    const f32x4 vzero = {0.f, 0.f, 0.f, 0.f};                                  \
    f32x4 acc[4][4];                                                           \
    _Pragma("unroll") for (int i = 0; i < 4; ++i)                              \
        _Pragma("unroll") for (int j = 0; j < 4; ++j) acc[i][j] = vzero;

#define GEMM_PREFETCH(KOFF, BUF)                                               \
    do {                                                                       \
        async_cp16(Ag + (KOFF),           &As[BUF][0][0] + woff0);             \
        async_cp16(Ag + (KOFF) + 64L * K, &As[BUF][0][0] + woff1);             \
        async_cp16(Bg + (KOFF),           &Bs[BUF][0][0] + woff0);             \
        async_cp16(Bg + (KOFF) + 64L * K, &Bs[BUF][0][0] + woff1);             \
    } while (0)

#define GEMM_KLOOP(KBASE, KEND)                                                \
    {                                                                          \
        GEMM_PREFETCH(KBASE, 0);                                               \
        int buf = 0;                                                           \
        for (int k0 = (KBASE); k0 < (KEND); k0 += BK, buf ^= 1) {              \
            __syncthreads();               /* tile(buf) resident in LDS */     \
            if (k0 + BK < (KEND)) GEMM_PREFETCH(k0 + BK, buf ^ 1);             \
            bf16x8 af[4], bfv[4];                                              \
            _Pragma("unroll") for (int i = 0; i < 4; ++i)                      \
                af[i]  = *(const bf16x8*)&As[buf][wm + i * 16 + fr][fq * 8];   \
            _Pragma("unroll") for (int j = 0; j < 4; ++j)                      \
                bfv[j] = *(const bf16x8*)&Bs[buf][wn + j * 16 + fr][fq * 8];   \
            _Pragma("unroll") for (int i = 0; i < 4; ++i)                      \
                _Pragma("unroll") for (int j = 0; j < 4; ++j)                  \
                    acc[i][j] = __builtin_amdgcn_mfma_f32_16x16x32_bf16(       \
                        af[i], bfv[j], acc[i][j], 0, 0, 0);                    \
        }                                                                      \
    }

// epilogue C/D layout: col = lane&15, row = (lane>>4)*4 + reg [m89/m91]
#define GEMM_EPILOGUE(DST, DT)                                                 \
    _Pragma("unroll") for (int i = 0; i < 4; ++i) {                            \
        _Pragma("unroll") for (int r = 0; r < 4; ++r) {                        \
            const int row = m0 + wm + i * 16 + fq * 4 + r;                     \
            _Pragma("unroll") for (int j = 0; j < 4; ++j) {                    \
                const int col = n0 + wn + j * 16 + fr;                         \
                (DST)[(long)row * N + col] = (DT)acc[i][j][r];                 \
            }                                                                  \
        }                                                                      \
    }

// full-K GEMM, batched via blockIdx.z (sB=0 broadcasts B)
template <typename OUT_T>
__global__ __launch_bounds__(256) void gemm_bt(
    const bf16* __restrict__ A, const bf16* __restrict__ B, OUT_T* __restrict__ C,
    const int M, const int N, const int K,
    const long sA, const long sB, const long sC)
{
    const bf16* Ab = A + blockIdx.z * sA;
    const bf16* Bb = B + blockIdx.z * sB;
    OUT_T*      Cb = C + blockIdx.z * sC;
    GEMM_PROLOGUE();
    GEMM_KLOOP(0, K);
    GEMM_EPILOGUE(Cb, OUT_T);
}

// split-K GEMM: blockIdx.z = batch*S + split; fp32 partials P[z][M*N]
__global__ __launch_bounds__(256) void gemm_splitk(
    const bf16* __restrict__ A, const bf16* __restrict__ B, float* __restrict__ P,
    const int M, const int N, const int K, const int Ksplit, const int S,
    const long sA, const long sB)
{
    const int zb = blockIdx.z / S;
    const int zs = blockIdx.z % S;
    const bf16* Ab = A + zb * sA;
    const bf16* Bb = B + zb * sB;
    float* Pb = P + (long)blockIdx.z * M * N;
    const int kbase = zs * Ksplit;
    GEMM_PROLOGUE();
    GEMM_KLOOP(kbase, kbase + Ksplit);
    GEMM_EPILOGUE(Pb, float);
}

// sum S fp32 partial planes -> bf16. grid (npb/1024, B), block 256.
__global__ __launch_bounds__(256) void reduce_splits(
    const float* __restrict__ P, bf16* __restrict__ out, const int npb, const int S)
{
    const int b = blockIdx.y;
    const long r = ((long)blockIdx.x * 256 + threadIdx.x) * 4;
    const float* base = P + (long)b * S * npb + r;
    float4 a = *(const float4*)(base);
    for (int s = 1; s < S; ++s) {
        const float4 v = *(const float4*)(base + (long)s * npb);
        a.x += v.x; a.y += v.y; a.z += v.z; a.w += v.w;
    }
    bf16x4 o;
    o[0] = (bf16)a.x; o[1] = (bf16)a.y; o[2] = (bf16)a.z; o[3] = (bf16)a.w;
    *(bf16x4*)(out + (long)b * npb + r) = o;
}

// ---------------------------------------------------------------------------
// O = h @ (W_q^T @ (h^T h)) per batch  — associativity-reordered reference.
// Workspace (106 MB when split-K enabled):
//   h  bf16 [B,L,H]  @ 0      | hT bf16 [B,H,L] @ 16M | Wt bf16 [H,H] @ 32M
//   G  bf16 [B,H,H]  @ 34M    | Mt bf16 [B,H,H] @ 38M | P fp32 (64 MB) @ 42M
// ---------------------------------------------------------------------------
extern "C" void kernel_launch(void* const* d_in, const int* in_sizes, int n_in,
                              void* d_out, int out_size, void* d_ws, size_t ws_size,
                              hipStream_t stream)
{
    const float* x  = (const float*)d_in[0];   // hidden_states [B,L,H]
    const float* Wq = (const float*)d_in[1];   // [H,H]
    const float* cs = (const float*)d_in[2];   // [L,H]
    const float* sn = (const float*)d_in[3];   // [L,H]
    float* out = (float*)d_out;                // [B,L,H] fp32
    char* ws = (char*)d_ws;

    bf16*  h  = (bf16*)(ws);
    bf16*  hT = (bf16*)(ws + 16u * 1024 * 1024);
    bf16*  Wt = (bf16*)(ws + 32u * 1024 * 1024);
    bf16*  G  = (bf16*)(ws + 34u * 1024 * 1024);
    bf16*  Mt = (bf16*)(ws + 38u * 1024 * 1024);
    float* P  = (float*)(ws + 42u * 1024 * 1024);   // 16 planes of H*H fp32

    const bool big_ws = ws_size >= (size_t)106 * 1024 * 1024;

    // 1) RoPE -> bf16 h
    rope_kernel<<<dim3(LL, BB), 128, 0, stream>>>(x, cs, sn, h);

    // 2) h -> hT (per batch [L,H] -> [H,L]) so the G GEMM has K contiguous
    transpose_bf16_64<<<dim3(LL / 64, HH / 64, BB), 256, 0, stream>>>(h, hT, LL, HH);

    // 3) W_q -> Wt = W_q^T in bf16
    transpose_wq<<<dim3(HH / 32, HH / 32), dim3(32, 32), 0, stream>>>(Wq, Wt);

    if (big_ws) {
        // 4) G_b = hT_b @ hT_b^T, K=4096 split 8 ways -> 1024 blocks (4/CU)
        gemm_splitk<<<dim3(HH / 128, HH / 128, BB * 8), 256, 0, stream>>>(
            hT, hT, P, HH, HH, LL, LL / 8, 8, (long)HH * LL, (long)HH * LL);
        reduce_splits<<<dim3(HH * HH / 1024, BB), 256, 0, stream>>>(P, G, HH * HH, 8);

        // 5) Mt_b = G_b @ Wt^T, K=1024 split 4 ways -> 512 blocks
        gemm_splitk<<<dim3(HH / 128, HH / 128, BB * 4), 256, 0, stream>>>(
            G, Wt, P, HH, HH, HH, HH / 4, 4, (long)HH * HH, 0L);
        reduce_splits<<<dim3(HH * HH / 1024, BB), 256, 0, stream>>>(P, Mt, HH * HH, 4);
    } else {
        // fallback: unsplit (latency-bound but correct in 42 MB ws)
        gemm_bt<bf16><<<dim3(HH / 128, HH / 128, BB), 256, 0, stream>>>(
            hT, hT, G, HH, HH, LL, (long)HH * LL, (long)HH * LL, (long)HH * HH);
        gemm_bt<bf16><<<dim3(HH / 128, HH / 128, BB), 256, 0, stream>>>(
            G, Wt, Mt, HH, HH, HH, (long)HH * HH, 0L, (long)HH * HH);
    }

    // 6) O_b = h_b @ Mt_b^T : O[l,j] = sum_i h[l,i] Mt[j,i]  -> fp32 out
    gemm_bt<float><<<dim3(LL / 128, HH / 128, BB), 256, 0, stream>>>(
        h, Mt, out, LL, HH, HH, (long)LL * HH, (long)HH * HH, (long)LL * HH);
}